// Round 10
// baseline (6661.874 us; speedup 1.0000x reference)
//
#include <hip/hip_runtime.h>
#include <cmath>
#include <cstring>

// Fixed problem shape: T=256, B=64, D=1024, H=1024
constexpr int TT = 256;
constexpr int BB = 64;
constexpr int DD = 1024;
constexpr int HH = 1024;
constexpr int KK = 2048;
constexpr int NBLK = 256;       // 1 block/CU, 4 hidden units each
constexpr int NTHR = 512;       // 8 waves = 4 M-tiles x 2 K-parities
constexpr int SEG = 8;          // steps per phase-1 segment
constexpr int NSEG = TT / SEG;
constexpr int HPB = 4;

// d_ws: [barrier flags: FLAG_UINTS uint32][zx: NBLK*SEG*256 float4]
constexpr int FLAG_UINTS = TT * 8 * 16 + TT * 16;   // 36864 uints

typedef __attribute__((ext_vector_type(8))) short bf16x8;
typedef __attribute__((ext_vector_type(4))) float f32x4;

__device__ __forceinline__ float sigm(float v) { return 1.0f / (1.0f + expf(-v)); }

// exact split: c == f32(hi<<16) + r, lo = trunc_bf16(r). Error of (hi,lo) pair ~2^-16 rel.
__device__ __forceinline__ void split2(float c, short& hi, short& lo) {
  unsigned u  = __float_as_uint(c);
  unsigned uh = u & 0xFFFF0000u;
  hi = (short)(uh >> 16);
  float r = c - __uint_as_float(uh);     // exact
  lo = (short)(__float_as_uint(r) >> 16);
}

// Two-level grid barrier on relaxed agent-scope atomics (no L2 wb/inv).
// Cross-block data (hx) moves via agent-scope (IC-coherent) atomics; each wave
// drains vmcnt before s_barrier (compiler-enforced), so arrival implies hx visible.
__device__ __forceinline__ void gridbar(unsigned* ws, int t, int tid, int bid) {
  __syncthreads();
  if (tid == 0) {
    asm volatile("s_waitcnt vmcnt(0)" ::: "memory");
    unsigned* grp  = ws + (size_t)(t * 8 + (bid >> 5)) * 16;
    unsigned* done = ws + 32768 + (size_t)t * 16;
    unsigned old = __hip_atomic_fetch_add(grp, 1u, __ATOMIC_RELAXED, __HIP_MEMORY_SCOPE_AGENT);
    if (old == 31u)
      __hip_atomic_fetch_add(done, 1u, __ATOMIC_RELAXED, __HIP_MEMORY_SCOPE_AGENT);
    while (__hip_atomic_load(done, __ATOMIC_RELAXED, __HIP_MEMORY_SCOPE_AGENT) < 8u)
      __builtin_amdgcn_s_sleep(1);
    asm volatile("" ::: "memory");
  }
  __syncthreads();
}

__global__ void zero_ws(unsigned* p, int n) {
  int i = blockIdx.x * blockDim.x + threadIdx.x;
  if (i < n) p[i] = 0u;
}

// LDS: Whi[16][2048] bf16 (64K, XOR-swizzled) + Wlo (64K) + zbuf[2][4][16][16] f32 (8K) = 136 KiB.
// comb (A operand) never touches LDS: each lane loads its own 8 fp32 from global, splits in regs.
__global__ __launch_bounds__(NTHR, 2)
void qlstm_mfma5(const float* __restrict__ x,
                 const float* __restrict__ Wf, const float* __restrict__ bf, const float* __restrict__ gbf,
                 const float* __restrict__ Wi, const float* __restrict__ bi, const float* __restrict__ gbi,
                 const float* __restrict__ Wu, const float* __restrict__ bu, const float* __restrict__ gbu,
                 const float* __restrict__ Wo, const float* __restrict__ bo, const float* __restrict__ gbo,
                 float* __restrict__ out, unsigned* __restrict__ ws)
{
  __shared__ __attribute__((aligned(16))) char smem[139264];   // 136 KiB
  char*  const Whi  = smem;                       // [16 col][2048 k] bf16, swizzled
  char*  const Wlo  = smem + 65536;
  float* const zbuf = (float*)(smem + 131072);    // [2 p][4 m][16 col][16 row]

  const int tid  = threadIdx.x;
  const int lane = tid & 63;
  const int wid  = tid >> 6;
  const int m    = wid & 3;        // M-tile (16 batch rows)
  const int p    = wid >> 2;       // K-parity
  const int arow = lane & 15;      // A row within tile / B col
  const int kseg = lane >> 4;      // k-segment (8 k's each)
  const int col  = lane & 15;
  const int bid  = blockIdx.x;
  const int h0   = bid * HPB;

  float* const wsz = (float*)ws + FLAG_UINTS;

  // ---- one-time: W -> LDS as bf16 hi/lo, XOR-swizzled (slot ^= col&7) ----
  {
    const float* Wg[4] = {Wf, Wi, Wu, Wo};
    for (int u = tid; u < 4096; u += NTHR) {
      const int c = u >> 8, s = u & 255;           // col, 16B-slot (8 k's)
      const float* src = Wg[c >> 2] + (size_t)(h0 + (c & 3)) * KK + s * 8;
      bf16x8 h8, l8;
      #pragma unroll
      for (int j = 0; j < 8; ++j) { short h, l; split2(src[j], h, l); h8[j] = h; l8[j] = l; }
      const int addr = (c * 4096 + s * 16) ^ ((c & 7) << 4);
      *(bf16x8*)(Whi + addr) = h8;
      *(bf16x8*)(Wlo + addr) = l8;
    }
  }

  // ---- cell-update thread state (tid<256: one (batch row, h_local) cell) ----
  const int urow = tid >> 2;
  const int uhl  = tid & 3;
  const int hcell = h0 + uhl;
  float bfv = 0, gbfv = 0, biv = 0, gbiv = 0, buv = 0, gbuv = 0, bov = 0, gbov = 0;
  if (tid < 256) {
    bfv = bf[hcell]; gbfv = gbf[hcell];
    biv = bi[hcell]; gbiv = gbi[hcell];
    buv = bu[hcell]; gbuv = gbu[hcell];
    bov = bo[hcell]; gbov = gbo[hcell];
  }
  float cx = 0.0f, hxl = 0.0f;

  auto ld8 = [](const float* ptr) -> float2 {   // 8B agent-scope (IC-coherent) load
    unsigned long long u = __hip_atomic_load((const unsigned long long*)(const void*)ptr,
                                             __ATOMIC_RELAXED, __HIP_MEMORY_SCOPE_AGENT);
    float2 r; __builtin_memcpy(&r, &u, 8); return r;
  };

  // one k-step: A-frag from c[8] (rows m*16+arow, k = kglob + kseg*8 + j), B from LDS W
  auto kstep = [&](const float c[8], int kglob, f32x4& acc) {
    bf16x8 ahi, alo;
    #pragma unroll
    for (int j = 0; j < 8; ++j) { short h, l; split2(c[j], h, l); ahi[j] = h; alo[j] = l; }
    const int ad = (col * 4096 + (kglob + kseg * 8) * 2) ^ ((col & 7) << 4);
    const bf16x8 bhi = *(const bf16x8*)(Whi + ad);
    const bf16x8 blo = *(const bf16x8*)(Wlo + ad);
    acc = __builtin_amdgcn_mfma_f32_16x16x32_bf16(ahi, bhi, acc, 0, 0, 0);
    acc = __builtin_amdgcn_mfma_f32_16x16x32_bf16(ahi, blo, acc, 0, 0, 0);
    acc = __builtin_amdgcn_mfma_f32_16x16x32_bf16(alo, bhi, acc, 0, 0, 0);
  };
  // C-frag write: col = lane&15, rows kseg*4..+4 (verified gfx950 C/D layout)
  auto writeC = [&](const f32x4 acc) {
    *(f32x4*)&zbuf[((p * 4 + m) * 16 + col) * 16 + kseg * 4] = acc;
  };

  __syncthreads();   // W visible to all waves

  for (int seg = 0; seg < NSEG; ++seg) {
    // ============ phase 1: x-projections (block-local, no grid syncs) ============
    for (int s = 0; s < SEG; ++s) {
      const int t = seg * SEG + s;
      f32x4 acc = {0.f, 0.f, 0.f, 0.f};
      const float* xrow = x + (size_t)t * BB * DD + (size_t)(m * 16 + arow) * DD;
      #pragma unroll 4
      for (int kb = 0; kb < 16; ++kb) {
        const int k0 = (kb * 2 + p) * 32;
        const float4 a0 = *(const float4*)(xrow + k0 + kseg * 8);
        const float4 a1 = *(const float4*)(xrow + k0 + kseg * 8 + 4);
        const float c[8] = {a0.x, a0.y, a0.z, a0.w, a1.x, a1.y, a1.z, a1.w};
        kstep(c, k0, acc);
      }
      writeC(acc);
      __syncthreads();
      if (tid < 256) {
        const int mr = urow >> 4, r = urow & 15;
        float4 z4;
        float* zz = (float*)&z4;
        #pragma unroll
        for (int g = 0; g < 4; ++g)
          zz[g] = zbuf[((0 + mr) * 16 + g * 4 + uhl) * 16 + r]
                + zbuf[((4 + mr) * 16 + g * 4 + uhl) * 16 + r];
        *(float4*)&wsz[((size_t)(bid * SEG + s) * 256 + tid) * 4] = z4;
      }
      __syncthreads();   // zbuf free for next step
    }

    // ============ phase 2: sequential steps (hx half only) ============
    for (int s = 0; s < SEG; ++s) {
      const int t = seg * SEG + s;
      f32x4 acc = {0.f, 0.f, 0.f, 0.f};
      if (t > 0) {
        const float* hrow = out + (size_t)(t - 1) * BB * HH + (size_t)(m * 16 + arow) * HH;
        #pragma unroll 4
        for (int kb = 0; kb < 16; ++kb) {
          const int k0 = (kb * 2 + p) * 32;
          const float* bptr = hrow + k0 + kseg * 8;
          const float2 q0 = ld8(bptr), q1 = ld8(bptr + 2), q2 = ld8(bptr + 4), q3 = ld8(bptr + 6);
          const float c[8] = {q0.x, q0.y, q1.x, q1.y, q2.x, q2.y, q3.x, q3.y};
          kstep(c, 1024 + k0, acc);
        }
      }
      writeC(acc);
      __syncthreads();

      if (tid < 256) {
        const float4 zx4 = *(const float4*)&wsz[((size_t)(bid * SEG + s) * 256 + tid) * 4];
        const int mr = urow >> 4, r = urow & 15;
        float zg[4];
        #pragma unroll
        for (int g = 0; g < 4; ++g)
          zg[g] = zbuf[((0 + mr) * 16 + g * 4 + uhl) * 16 + r]
                + zbuf[((4 + mr) * 16 + g * 4 + uhl) * 16 + r];
        const float zf = bfv + zx4.x + zg[0];
        const float zi = biv + zx4.y + zg[1];
        const float zu = buv + zx4.z + zg[2];
        const float zo = bov + zx4.w + zg[3];
        const float fg = sigm(cosf(zf) + gbfv);   // QLinearGate: cos(z)+gb
        const float ig = sigm(cosf(zi) + gbiv);
        const float gg = tanhf(cosf(zu) + gbuv);
        const float og = sigm(cosf(zo) + gbov);
        cx = fg * cx + ig * gg;
        const float hx = og * tanhf(cx);
        __hip_atomic_store(&out[(size_t)t * BB * HH + (size_t)urow * HH + hcell], hx,
                           __ATOMIC_RELAXED, __HIP_MEMORY_SCOPE_AGENT);
        hxl = hx;
      }

      gridbar(ws, t, tid, bid);   // hx(t) globally visible before step t+1
    }
  }

  if (tid < 256) {
    float* hxout = out + (size_t)TT * BB * HH;
    float* cxout = hxout + (size_t)BB * HH;
    hxout[(size_t)urow * HH + hcell] = hxl;
    cxout[(size_t)urow * HH + hcell] = cx;
  }
}

extern "C" void kernel_launch(void* const* d_in, const int* in_sizes, int n_in,
                              void* d_out, int out_size, void* d_ws, size_t ws_size,
                              hipStream_t stream) {
  const float* x   = (const float*)d_in[0];
  const float* Wf  = (const float*)d_in[1];
  const float* bf_ = (const float*)d_in[2];
  const float* gbf = (const float*)d_in[3];
  const float* Wi  = (const float*)d_in[4];
  const float* bi_ = (const float*)d_in[5];
  const float* gbi = (const float*)d_in[6];
  const float* Wu  = (const float*)d_in[7];
  const float* bu_ = (const float*)d_in[8];
  const float* gbu = (const float*)d_in[9];
  const float* Wo  = (const float*)d_in[10];
  const float* bo_ = (const float*)d_in[11];
  const float* gbo = (const float*)d_in[12];
  float* out = (float*)d_out;
  unsigned* wsp = (unsigned*)d_ws;

  // barrier counters are poisoned 0xAA before every launch -> zero them first
  zero_ws<<<(FLAG_UINTS + 255) / 256, 256, 0, stream>>>(wsp, FLAG_UINTS);

  void* args[] = {&x, &Wf, &bf_, &gbf, &Wi, &bi_, &gbi, &Wu, &bu_, &gbu,
                  &Wo, &bo_, &gbo, &out, &wsp};
  hipLaunchCooperativeKernel((void*)qlstm_mfma5, dim3(NBLK), dim3(NTHR),
                             args, 0, stream);
}